// Round 10
// baseline (223.954 us; speedup 1.0000x reference)
//
#include <hip/hip_runtime.h>

#define B 32
#define CL 1536
#define CG 192
#define T 256
#define MI 512
#define NPOS 8192   /* B*T */
#define EPS 1e-5f
#define TEMP 0.07f

typedef __attribute__((ext_vector_type(8))) __bf16 bf16x8;
typedef __attribute__((ext_vector_type(4))) float f32x4;

__device__ __forceinline__ unsigned short f2bf(float f) {
  union { float f; unsigned u; } v; v.f = f;
  unsigned r = v.u + 0x7FFFu + ((v.u >> 16) & 1u);
  return (unsigned short)(r >> 16);
}
__device__ __forceinline__ float bf2f(unsigned short h) {
  union { unsigned u; float f; } v; v.u = ((unsigned)h) << 16;
  return v.f;
}

__device__ __forceinline__ float wave_sum(float v) {
#pragma unroll
  for (int off = 32; off > 0; off >>= 1) v += __shfl_xor(v, off, 64);
  return v;
}
__device__ __forceinline__ float block_sum(float v, float* rb) {
  v = wave_sum(v);
  __syncthreads();
  if ((threadIdx.x & 63) == 0) rb[threadIdx.x >> 6] = v;
  __syncthreads();
  return rb[0] + rb[1] + rb[2] + rb[3];
}

// ============ 1: prep = weight casts + x transpose + gnet1 + zero bn ========
__global__ __launch_bounds__(256) void k_prep(
    const float* __restrict__ x, const float* __restrict__ lW1,
    const float* __restrict__ lWs, const float* __restrict__ lW2,
    const float* __restrict__ gx, const float* __restrict__ gW1,
    unsigned short* __restrict__ xT, unsigned short* __restrict__ Wc,
    unsigned short* __restrict__ W2b, float* __restrict__ y1g,
    float* __restrict__ bsum) {
  __shared__ float xs[64][65];
  const int bi = blockIdx.x, tid = threadIdx.x;
  if (bi < 1792) {
    int idx = (bi * 256 + tid) * 4;
    const float* src; unsigned short* dst;
    if (idx < 786432) { src = lW1 + idx; dst = Wc + idx; }
    else if (idx < 1572864) { src = lWs + (idx - 786432); dst = Wc + idx; }
    else { src = lW2 + (idx - 1572864); dst = W2b + (idx - 1572864); }
    float4 v = *(const float4*)src;
    ushort4 o = {f2bf(v.x), f2bf(v.y), f2bf(v.z), f2bf(v.w)};
    *(ushort4*)dst = o;
  } else if (bi < 4864) {
    int bi2 = bi - 1792;
    int b = bi2 / 96, rem = bi2 - b * 96;
    int c0 = (rem >> 2) * 64, t0 = (rem & 3) * 64;
    const float* xb = x + ((size_t)b * CL + c0) * T + t0;
#pragma unroll
    for (int i = 0; i < 16; i++) {
      int idx = tid + i * 256, c = idx >> 6, t = idx & 63;
      xs[c][t] = xb[(size_t)c * T + t];
    }
    __syncthreads();
    unsigned short* ob = xT + ((size_t)b * T + t0) * CL + c0;
#pragma unroll
    for (int half = 0; half < 2; half++) {
      int s = tid + half * 256;
      int t = s >> 3, kg = s & 7;
      unsigned short v[8];
#pragma unroll
      for (int j = 0; j < 8; j++) v[j] = f2bf(xs[kg * 8 + j][t]);
      uint4 o = {(unsigned)v[0] | ((unsigned)v[1] << 16),
                 (unsigned)v[2] | ((unsigned)v[3] << 16),
                 (unsigned)v[4] | ((unsigned)v[5] << 16),
                 (unsigned)v[6] | ((unsigned)v[7] << 16)};
      *(uint4*)&ob[(size_t)t * CL + kg * 8] = o;
    }
  } else if (bi < 4928) {
    int idx = (bi - 4864) * 256 + tid;
    int b = idx & 31, o = idx >> 5;
    float s = 0.f;
    for (int c = 0; c < CG; c++) s = fmaf(gx[b * CG + c], gW1[o * CG + c], s);
    y1g[o * 32 + b] = s;
  } else {
    float4 z = {0.f, 0.f, 0.f, 0.f};
    ((float4*)bsum)[tid] = z;  // zeroes bsum[512] + bsq[512] (adjacent)
  }
}

// ============ 2: gemm1 dual MFMA (256thr, 128x128, BK=32) ===================
// LDS layout: two tile-rows per 128B LDS row, chunk XOR-swizzled (R6-proven
// conflict-free geometry). grid: 512 GEMM blocks + 64 gnet2 blocks.
__global__ __launch_bounds__(256, 2) void k_gemm1(
    const unsigned short* __restrict__ xT, const unsigned short* __restrict__ Wc,
    unsigned short* __restrict__ y1u, unsigned short* __restrict__ ysb,
    float* __restrict__ bsum, float* __restrict__ bsq,
    const float* __restrict__ y1g, const float* __restrict__ gg1,
    const float* __restrict__ gb1, const float* __restrict__ gW2,
    const float* __restrict__ gb2, const float* __restrict__ gx,
    const float* __restrict__ gWsc, float* __restrict__ hg) {
  const int tid = threadIdx.x, bi = blockIdx.x;
  if (bi >= 512) {  // gnet2 with redundant per-block gbn (tiny)
    __shared__ float gsc[512], gsh[512];
#pragma unroll
    for (int jj = 0; jj < 2; jj++) {
      int o = tid + jj * 256;
      float s = 0.f, s2 = 0.f;
      for (int b = 0; b < 32; b++) {
        float v = y1g[o * 32 + b];
        s += v; s2 = fmaf(v, v, s2);
      }
      float mu = s * (1.f / 32.f);
      float var = s2 * (1.f / 32.f) - mu * mu;
      float sc = gg1[o] * rsqrtf(var + EPS);
      gsc[o] = sc;
      gsh[o] = gb1[o] - mu * sc;
    }
    __syncthreads();
    int idx = (bi - 512) * 256 + tid;
    int b = idx & 31, p = idx >> 5;
    float s = gb2[p];
    for (int o = 0; o < MI; o++) {
      float v = fmaxf(fmaf(y1g[o * 32 + b], gsc[o], gsh[o]), 0.f);
      s = fmaf(v, gW2[(size_t)p * MI + o], s);
    }
    for (int c = 0; c < CG; c++) s = fmaf(gx[b * CG + c], gWsc[p * CG + c], s);
    hg[p * 32 + b] = s;
    return;
  }
  __shared__ __align__(16) unsigned short As[64 * 64];  // [r2 0..63][128B row]
  __shared__ __align__(16) unsigned short Bs[64 * 64];
  const int w = tid >> 6, lane = tid & 63;
  const int m0 = (bi & 63) * 128, o0 = (bi >> 6) * 128;
  const int wm = w & 1, wn = w >> 1;
  const int lm = lane & 15, q = lane >> 4;
  // DMA source mapping: lane l -> (tile-row, k-chunk) for swizzled LDS store
  const int cswz = (lane & 7) ^ (lane >> 3);          // logical chunk c
  const int trow = ((lane >> 3) << 1) | (cswz >> 2);  // tile-row in 16-row grp
  const int kq8 = (cswz & 3) * 8;                     // k element offset
  // Fragment read base: row pairing + chunk XOR (per-lane constants)
  const int h = lm >> 1;
  const int fcol = (((((lm & 1) << 2) | q)) ^ h) * 8;
  const int fa = (wm * 32 + h) * 64 + fcol;
  const int fb = (wn * 32 + h) * 64 + fcol;
  f32x4 acc[4][4];
#pragma unroll
  for (int i = 0; i < 4; i++)
#pragma unroll
    for (int j = 0; j < 4; j++) acc[i][j] = f32x4{0.f, 0.f, 0.f, 0.f};

  const unsigned short* pa0 = xT + (size_t)(m0 + w * 32 + trow) * CL + kq8;
  const unsigned short* pa1 = pa0 + (size_t)16 * CL;
  const unsigned short* pb0 = Wc + (size_t)(o0 + w * 32 + trow) * CL + kq8;
  const unsigned short* pb1 = pb0 + (size_t)16 * CL;
  for (int c0 = 0; c0 < CL; c0 += 32) {
    __builtin_amdgcn_global_load_lds(
        (const __attribute__((address_space(1))) void*)(pa0 + c0),
        (__attribute__((address_space(3))) void*)&As[(w * 16) * 64], 16, 0, 0);
    __builtin_amdgcn_global_load_lds(
        (const __attribute__((address_space(1))) void*)(pa1 + c0),
        (__attribute__((address_space(3))) void*)&As[(w * 16 + 8) * 64], 16, 0, 0);
    __builtin_amdgcn_global_load_lds(
        (const __attribute__((address_space(1))) void*)(pb0 + c0),
        (__attribute__((address_space(3))) void*)&Bs[(w * 16) * 64], 16, 0, 0);
    __builtin_amdgcn_global_load_lds(
        (const __attribute__((address_space(1))) void*)(pb1 + c0),
        (__attribute__((address_space(3))) void*)&Bs[(w * 16 + 8) * 64], 16, 0, 0);
    __syncthreads();
    bf16x8 af[4], bfr[4];
#pragma unroll
    for (int mi = 0; mi < 4; mi++)
      af[mi] = *(const bf16x8*)&As[fa + mi * 512];
#pragma unroll
    for (int ni = 0; ni < 4; ni++)
      bfr[ni] = *(const bf16x8*)&Bs[fb + ni * 512];
#pragma unroll
    for (int mi = 0; mi < 4; mi++)
#pragma unroll
      for (int ni = 0; ni < 4; ni++)
        acc[mi][ni] = __builtin_amdgcn_mfma_f32_16x16x32_bf16(
            af[mi], bfr[ni], acc[mi][ni], 0, 0, 0);
    __syncthreads();
  }
  const int row0 = m0 + wm * 64 + q * 4;
  const bool isY1 = (o0 < 512);
  unsigned short* dst = isY1 ? y1u : ysb;
  const int ob = isY1 ? o0 : o0 - 512;
#pragma unroll
  for (int mi = 0; mi < 4; mi++)
#pragma unroll
    for (int ni = 0; ni < 4; ni++) {
      int oc = ob + wn * 64 + ni * 16 + lm;
#pragma unroll
      for (int r = 0; r < 4; r++)
        dst[(size_t)(row0 + mi * 16 + r) * 512 + oc] = f2bf(acc[mi][ni][r]);
    }
  if (isY1) {  // BN stats: in-register col sums + q-shuffle + 1 atomic per col
#pragma unroll
    for (int ni = 0; ni < 4; ni++) {
      float s = 0.f, s2 = 0.f;
#pragma unroll
      for (int mi = 0; mi < 4; mi++)
#pragma unroll
        for (int r = 0; r < 4; r++) {
          float v = acc[mi][ni][r];
          s += v; s2 = fmaf(v, v, s2);
        }
      s += __shfl_xor(s, 16, 64);  s2 += __shfl_xor(s2, 16, 64);
      s += __shfl_xor(s, 32, 64);  s2 += __shfl_xor(s2, 32, 64);
      if (q == 0) {
        int c = o0 + wn * 64 + ni * 16 + lm;
        atomicAdd(&bsum[c], s);
        atomicAdd(&bsq[c], s2);
      }
    }
  }
}

// ============ 3: bnapply (v = bf16(relu(bn(y1)))) + gln piggyback ===========
__global__ __launch_bounds__(256) void k_bnapp(
    const unsigned short* __restrict__ y1u, const float* __restrict__ bsum,
    const float* __restrict__ bsq, const float* __restrict__ lg1,
    const float* __restrict__ lb1, unsigned short* __restrict__ vv,
    const float* __restrict__ hg, const float* __restrict__ glng,
    const float* __restrict__ glnb, unsigned short* __restrict__ gnormb) {
  __shared__ float rb[4];
  const int bi = blockIdx.x, tid = threadIdx.x;
  if (bi >= 4096) {  // gln
    int b = bi - 4096;
    float v0 = hg[tid * 32 + b];
    float v1 = hg[(tid + 256) * 32 + b];
    float s = block_sum(v0 + v1, rb);
    float s2 = block_sum(fmaf(v0, v0, v1 * v1), rb);
    float mu = s * (1.f / MI);
    float var = s2 * (1.f / MI) - mu * mu;
    float rstd = rsqrtf(var + EPS);
    float L0 = fmaf((v0 - mu) * rstd, glng[tid], glnb[tid]);
    float L1 = fmaf((v1 - mu) * rstd, glng[tid + 256], glnb[tid + 256]);
    float n2 = block_sum(fmaf(L0, L0, L1 * L1), rb);
    float inv = rsqrtf(n2);
    gnormb[b * MI + tid] = f2bf(L0 * inv);
    gnormb[b * MI + tid + 256] = f2bf(L1 * inv);
    return;
  }
  int idx = (bi * 256 + tid) * 4;
  int o = idx & 511;
  ushort4 in = *(const ushort4*)&y1u[idx];
  float iv[4] = {bf2f(in.x), bf2f(in.y), bf2f(in.z), bf2f(in.w)};
  unsigned short ov[4];
#pragma unroll
  for (int j = 0; j < 4; j++) {
    float mu = bsum[o + j] * (1.f / NPOS);
    float var = bsq[o + j] * (1.f / NPOS) - mu * mu;
    float sc = lg1[o + j] * rsqrtf(var + EPS);
    float sh = lb1[o + j] - mu * sc;
    ov[j] = f2bf(fmaxf(fmaf(iv[j], sc, sh), 0.f));
  }
  ushort4 out = {ov[0], ov[1], ov[2], ov[3]};
  *(ushort4*)&vv[idx] = out;
}

// ============ 4: gemm2 (256thr, 128x128, BK=32, swizzled LDS) ===============
__global__ __launch_bounds__(256, 2) void k_gemm2(
    const unsigned short* __restrict__ vv, const unsigned short* __restrict__ W2b,
    const float* __restrict__ b2, unsigned short* __restrict__ hb16) {
  __shared__ __align__(16) unsigned short As[64 * 64];
  __shared__ __align__(16) unsigned short Bs[64 * 64];
  const int tid = threadIdx.x, bi = blockIdx.x;
  const int w = tid >> 6, lane = tid & 63;
  const int m0 = (bi & 63) * 128, p0 = (bi >> 6) * 128;
  const int wm = w & 1, wn = w >> 1;
  const int lm = lane & 15, q = lane >> 4;
  const int cswz = (lane & 7) ^ (lane >> 3);
  const int trow = ((lane >> 3) << 1) | (cswz >> 2);
  const int kq8 = (cswz & 3) * 8;
  const int h = lm >> 1;
  const int fcol = (((((lm & 1) << 2) | q)) ^ h) * 8;
  const int fa = (wm * 32 + h) * 64 + fcol;
  const int fb = (wn * 32 + h) * 64 + fcol;
  f32x4 acc[4][4];
#pragma unroll
  for (int i = 0; i < 4; i++)
#pragma unroll
    for (int j = 0; j < 4; j++) acc[i][j] = f32x4{0.f, 0.f, 0.f, 0.f};

  const unsigned short* pa0 = vv + (size_t)(m0 + w * 32 + trow) * 512 + kq8;
  const unsigned short* pa1 = pa0 + (size_t)16 * 512;
  const unsigned short* pb0 = W2b + (size_t)(p0 + w * 32 + trow) * 512 + kq8;
  const unsigned short* pb1 = pb0 + (size_t)16 * 512;
  for (int c0 = 0; c0 < 512; c0 += 32) {
    __builtin_amdgcn_global_load_lds(
        (const __attribute__((address_space(1))) void*)(pa0 + c0),
        (__attribute__((address_space(3))) void*)&As[(w * 16) * 64], 16, 0, 0);
    __builtin_amdgcn_global_load_lds(
        (const __attribute__((address_space(1))) void*)(pa1 + c0),
        (__attribute__((address_space(3))) void*)&As[(w * 16 + 8) * 64], 16, 0, 0);
    __builtin_amdgcn_global_load_lds(
        (const __attribute__((address_space(1))) void*)(pb0 + c0),
        (__attribute__((address_space(3))) void*)&Bs[(w * 16) * 64], 16, 0, 0);
    __builtin_amdgcn_global_load_lds(
        (const __attribute__((address_space(1))) void*)(pb1 + c0),
        (__attribute__((address_space(3))) void*)&Bs[(w * 16 + 8) * 64], 16, 0, 0);
    __syncthreads();
    bf16x8 af[4], bfr[4];
#pragma unroll
    for (int mi = 0; mi < 4; mi++)
      af[mi] = *(const bf16x8*)&As[fa + mi * 512];
#pragma unroll
    for (int ni = 0; ni < 4; ni++)
      bfr[ni] = *(const bf16x8*)&Bs[fb + ni * 512];
#pragma unroll
    for (int mi = 0; mi < 4; mi++)
#pragma unroll
      for (int ni = 0; ni < 4; ni++)
        acc[mi][ni] = __builtin_amdgcn_mfma_f32_16x16x32_bf16(
            af[mi], bfr[ni], acc[mi][ni], 0, 0, 0);
    __syncthreads();
  }
  const int row0 = m0 + wm * 64 + q * 4;
#pragma unroll
  for (int ni = 0; ni < 4; ni++) {
    int p = p0 + wn * 64 + ni * 16 + lm;
    float bias = b2[p];
#pragma unroll
    for (int mi = 0; mi < 4; mi++)
#pragma unroll
      for (int r = 0; r < 4; r++) {
        size_t off = (size_t)(row0 + mi * 16 + r) * 512 + p;
        hb16[off] = f2bf(acc[mi][ni][r] + bias);  // +ys added in tail
      }
  }
}

// ============ 5: tail = (+ys) LN + U-tile MFMA + positives + partials =======
__global__ __launch_bounds__(256) void k_tail(
    const unsigned short* __restrict__ hb16, const unsigned short* __restrict__ ysb,
    const float* __restrict__ lng, const float* __restrict__ lnb,
    const unsigned short* __restrict__ gnormb,
    float* __restrict__ up, float* __restrict__ pmax, float* __restrict__ psum) {
  __shared__ __align__(16) unsigned short gs[32 * 512];
  __shared__ __align__(16) unsigned short Ls[32 * 512];
  __shared__ float Ured[4 * 1024];
  const int tid = threadIdx.x;
  const int w = tid >> 6, lane = tid & 63;
  const int r0 = blockIdx.x * 32;
  const int smp = r0 >> 8;
#pragma unroll
  for (int i = 0; i < 8; i++) {
    int e = (tid + i * 256) * 8;
    *(uint4*)&gs[e] = *(const uint4*)&gnormb[e];
  }
  float4 g0 = *(const float4*)&lng[lane * 8];
  float4 g1 = *(const float4*)&lng[lane * 8 + 4];
  float4 bb0 = *(const float4*)&lnb[lane * 8];
  float4 bb1 = *(const float4*)&lnb[lane * 8 + 4];
  float gg[8] = {g0.x, g0.y, g0.z, g0.w, g1.x, g1.y, g1.z, g1.w};
  float bz[8] = {bb0.x, bb0.y, bb0.z, bb0.w, bb1.x, bb1.y, bb1.z, bb1.w};
#pragma unroll
  for (int j = 0; j < 8; j++) {
    int rr = w * 8 + j;
    size_t off = (size_t)(r0 + rr) * 512 + lane * 8;
    uint4 hu = *(const uint4*)&hb16[off];
    uint4 yu = *(const uint4*)&ysb[off];
    unsigned short hv[8] = {
        (unsigned short)(hu.x & 0xffff), (unsigned short)(hu.x >> 16),
        (unsigned short)(hu.y & 0xffff), (unsigned short)(hu.y >> 16),
        (unsigned short)(hu.z & 0xffff), (unsigned short)(hu.z >> 16),
        (unsigned short)(hu.w & 0xffff), (unsigned short)(hu.w >> 16)};
    unsigned short yv[8] = {
        (unsigned short)(yu.x & 0xffff), (unsigned short)(yu.x >> 16),
        (unsigned short)(yu.y & 0xffff), (unsigned short)(yu.y >> 16),
        (unsigned short)(yu.z & 0xffff), (unsigned short)(yu.z >> 16),
        (unsigned short)(yu.w & 0xffff), (unsigned short)(yu.w >> 16)};
    float v[8];
    float s = 0.f, s2 = 0.f;
#pragma unroll
    for (int k = 0; k < 8; k++) {
      v[k] = bf2f(hv[k]) + bf2f(yv[k]);
      s += v[k]; s2 = fmaf(v[k], v[k], s2);
    }
    s = wave_sum(s);
    s2 = wave_sum(s2);
    float mu = s * (1.f / MI);
    float var = s2 * (1.f / MI) - mu * mu;
    float rstd = rsqrtf(var + EPS);
    float L[8], n2 = 0.f;
#pragma unroll
    for (int k = 0; k < 8; k++) {
      L[k] = fmaf((v[k] - mu) * rstd, gg[k], bz[k]);
      n2 = fmaf(L[k], L[k], n2);
    }
    n2 = wave_sum(n2);
    float inv = rsqrtf(n2);
    unsigned short* orow = &Ls[rr * 512 + lane * 8];
    ushort4 o0 = {f2bf(L[0] * inv), f2bf(L[1] * inv), f2bf(L[2] * inv), f2bf(L[3] * inv)};
    ushort4 o1 = {f2bf(L[4] * inv), f2bf(L[5] * inv), f2bf(L[6] * inv), f2bf(L[7] * inv)};
    *(ushort4*)orow = o0;
    *(ushort4*)(orow + 4) = o1;
  }
  __syncthreads();
  const int lm = lane & 15, q = lane >> 4;
  f32x4 acc[2][2];
#pragma unroll
  for (int i = 0; i < 2; i++)
#pragma unroll
    for (int j = 0; j < 2; j++) acc[i][j] = f32x4{0.f, 0.f, 0.f, 0.f};
#pragma unroll
  for (int kk = 0; kk < 4; kk++) {
    int k0 = w * 128 + kk * 32 + q * 8;
    bf16x8 af[2], bfr[2];
#pragma unroll
    for (int mi = 0; mi < 2; mi++)
      af[mi] = *(const bf16x8*)&gs[(mi * 16 + lm) * 512 + k0];
#pragma unroll
    for (int ni = 0; ni < 2; ni++)
      bfr[ni] = *(const bf16x8*)&Ls[(ni * 16 + lm) * 512 + k0];
#pragma unroll
    for (int mi = 0; mi < 2; mi++)
#pragma unroll
      for (int ni = 0; ni < 2; ni++)
        acc[mi][ni] = __builtin_amdgcn_mfma_f32_16x16x32_bf16(
            af[mi], bfr[ni], acc[mi][ni], 0, 0, 0);
  }
#pragma unroll
  for (int mi = 0; mi < 2; mi++)
#pragma unroll
    for (int ni = 0; ni < 2; ni++)
#pragma unroll
      for (int r = 0; r < 4; r++) {
        int m = mi * 16 + q * 4 + r, n = ni * 16 + lm;
        Ured[w * 1024 + m * 32 + n] = acc[mi][ni][r];
      }
  __syncthreads();
  float u[4];
#pragma unroll
  for (int j = 0; j < 4; j++) {
    int idx = tid * 4 + j;
    u[j] = Ured[idx] + Ured[1024 + idx] + Ured[2048 + idx] + Ured[3072 + idx];
  }
  __syncthreads();
#pragma unroll
  for (int j = 0; j < 4; j++) Ured[tid * 4 + j] = u[j];
  int m = (tid * 4) >> 5;
  if (m == smp) {
#pragma unroll
    for (int j = 0; j < 4; j++)
      up[r0 + ((tid * 4 + j) & 31)] = u[j] * (1.f / TEMP);
  }
  __syncthreads();
  if (tid < 32) {
    float mx = -1e30f, s = 0.f;
    if (tid != smp) {
      for (int n = 0; n < 32; n++) mx = fmaxf(mx, Ured[tid * 32 + n]);
      for (int n = 0; n < 32; n++) s += expf(Ured[tid * 32 + n] - mx);
    }
    pmax[tid * 256 + blockIdx.x] = mx;
    psum[tid * 256 + blockIdx.x] = s;
  }
}

// ============ 6: loss = mean(lse - u_p), combining 256 partials/row =========
__global__ __launch_bounds__(256) void k_loss(
    const float* __restrict__ up, const float* __restrict__ pmax,
    const float* __restrict__ psum, float* __restrict__ out) {
  __shared__ float rb[4];
  __shared__ float red[32][8];
  __shared__ float Ms[32], Ss[32];
  const int tid = threadIdx.x;
  const int n = tid >> 3, j = tid & 7;
  float mx = -1e30f;
  for (int c = j * 32; c < j * 32 + 32; c++) mx = fmaxf(mx, pmax[n * 256 + c]);
  red[n][j] = mx;
  __syncthreads();
  if (j == 0) {
    float M = -1e30f;
#pragma unroll
    for (int k = 0; k < 8; k++) M = fmaxf(M, red[n][k]);
    Ms[n] = M;
  }
  __syncthreads();
  float M = Ms[n];
  float s = 0.f;
  for (int c = j * 32; c < j * 32 + 32; c++)
    s += psum[n * 256 + c] * expf(pmax[n * 256 + c] - M);
  __syncthreads();
  red[n][j] = s;
  __syncthreads();
  if (j == 0) {
    float S = 0.f;
#pragma unroll
    for (int k = 0; k < 8; k++) S += red[n][k];
    Ss[n] = S;
  }
  __syncthreads();
  float acc = 0.f;
  for (int i = tid; i < NPOS; i += 256) {
    int nn = i >> 8;
    float upv = up[i];
    float Mn = Ms[nn], Sn = Ss[nn];
    float mx2 = fmaxf(upv, Mn);
    float lse = mx2 + logf(expf(upv - mx2) + Sn * expf(Mn - mx2));
    acc += lse - upv;
  }
  acc = block_sum(acc, rb);
  if (tid == 0) out[0] = acc * (1.f / NPOS);
}

extern "C" void kernel_launch(void* const* d_in, const int* in_sizes, int n_in,
                              void* d_out, int out_size, void* d_ws, size_t ws_size,
                              hipStream_t stream) {
  (void)in_sizes; (void)n_in; (void)out_size; (void)ws_size;
  const float* x    = (const float*)d_in[0];
  const float* gx   = (const float*)d_in[1];
  const float* lW1  = (const float*)d_in[2];
  const float* lg1  = (const float*)d_in[3];
  const float* lb1  = (const float*)d_in[4];
  const float* lW2  = (const float*)d_in[5];
  const float* lb2  = (const float*)d_in[6];
  const float* lWs  = (const float*)d_in[7];
  const float* llng = (const float*)d_in[8];
  const float* llnb = (const float*)d_in[9];
  const float* gW1  = (const float*)d_in[10];
  const float* gg1  = (const float*)d_in[11];
  const float* gb1  = (const float*)d_in[12];
  const float* gW2  = (const float*)d_in[13];
  const float* gb2  = (const float*)d_in[14];
  const float* gWs  = (const float*)d_in[15];
  const float* glng = (const float*)d_in[16];
  const float* glnb = (const float*)d_in[17];

  char* wsb = (char*)d_ws;
  unsigned short* xT     = (unsigned short*)(wsb);             // [8192][1536] bf16
  unsigned short* Wc     = (unsigned short*)(wsb + 25165824);  // [1024][1536] bf16
  unsigned short* W2b    = (unsigned short*)(wsb + 28311552);  // [512][512] bf16
  unsigned short* y1u    = (unsigned short*)(wsb + 28835840);  // [8192][512] bf16
  unsigned short* ysb    = (unsigned short*)(wsb + 37224448);  // [8192][512] bf16
  unsigned short* vv     = (unsigned short*)(wsb + 45613056);  // [8192][512] bf16
  unsigned short* hb16   = (unsigned short*)(wsb + 54001664);  // [8192][512] bf16
  float* bsum            = (float*)(wsb + 62390272);           // [512]
  float* bsq             = (float*)(wsb + 62392320);           // [512]
  float* y1g             = (float*)(wsb + 62394368);           // [512][32]
  float* hg              = (float*)(wsb + 62459904);           // [512][32]
  unsigned short* gnormb = (unsigned short*)(wsb + 62525440);  // [32][512] bf16
  float* up              = (float*)(wsb + 62558208);           // [8192]
  float* pmax            = (float*)(wsb + 62590976);           // [32][256]
  float* psum            = (float*)(wsb + 62623744);           // [32][256]

  k_prep<<<dim3(4929), 256, 0, stream>>>(x, lW1, lWs, lW2, gx, gW1, xT, Wc, W2b,
                                         y1g, bsum);
  k_gemm1<<<dim3(576), 256, 0, stream>>>(xT, Wc, y1u, ysb, bsum, bsq,
                                         y1g, gg1, gb1, gW2, gb2, gx, gWs, hg);
  k_bnapp<<<dim3(4128), 256, 0, stream>>>(y1u, bsum, bsq, lg1, lb1, vv,
                                          hg, glng, glnb, gnormb);
  k_gemm2<<<dim3(256), 256, 0, stream>>>(vv, W2b, lb2, hb16);
  k_tail<<<dim3(256), 256, 0, stream>>>(hb16, ysb, llng, llnb, gnormb,
                                        up, pmax, psum);
  k_loss<<<dim3(1), 256, 0, stream>>>(up, pmax, psum, (float*)d_out);
}

// Round 11
// 217.166 us; speedup vs baseline: 1.0313x; 1.0313x over previous
//
#include <hip/hip_runtime.h>

#define B 32
#define CL 1536
#define CG 192
#define T 256
#define MI 512
#define NPOS 8192   /* B*T */
#define EPS 1e-5f
#define TEMP 0.07f

typedef __attribute__((ext_vector_type(8))) __bf16 bf16x8;
typedef __attribute__((ext_vector_type(4))) float f32x4;

__device__ __forceinline__ unsigned short f2bf(float f) {
  union { float f; unsigned u; } v; v.f = f;
  unsigned r = v.u + 0x7FFFu + ((v.u >> 16) & 1u);
  return (unsigned short)(r >> 16);
}
__device__ __forceinline__ float bf2f(unsigned short h) {
  union { unsigned u; float f; } v; v.u = ((unsigned)h) << 16;
  return v.f;
}

__device__ __forceinline__ float wave_sum(float v) {
#pragma unroll
  for (int off = 32; off > 0; off >>= 1) v += __shfl_xor(v, off, 64);
  return v;
}
__device__ __forceinline__ float block_sum(float v, float* rb) {
  v = wave_sum(v);
  __syncthreads();
  if ((threadIdx.x & 63) == 0) rb[threadIdx.x >> 6] = v;
  __syncthreads();
  return rb[0] + rb[1] + rb[2] + rb[3];
}

// ============ 1: prep = weight casts + x transpose + gnet1 + zero bn ========
__global__ __launch_bounds__(256) void k_prep(
    const float* __restrict__ x, const float* __restrict__ lW1,
    const float* __restrict__ lWs, const float* __restrict__ lW2,
    const float* __restrict__ gx, const float* __restrict__ gW1,
    unsigned short* __restrict__ xT, unsigned short* __restrict__ Wc,
    unsigned short* __restrict__ W2b, float* __restrict__ y1g,
    float* __restrict__ bsum) {
  __shared__ float xs[64][65];
  const int bi = blockIdx.x, tid = threadIdx.x;
  if (bi < 1792) {
    int idx = (bi * 256 + tid) * 4;
    const float* src; unsigned short* dst;
    if (idx < 786432) { src = lW1 + idx; dst = Wc + idx; }
    else if (idx < 1572864) { src = lWs + (idx - 786432); dst = Wc + idx; }
    else { src = lW2 + (idx - 1572864); dst = W2b + (idx - 1572864); }
    float4 v = *(const float4*)src;
    ushort4 o = {f2bf(v.x), f2bf(v.y), f2bf(v.z), f2bf(v.w)};
    *(ushort4*)dst = o;
  } else if (bi < 4864) {
    int bi2 = bi - 1792;
    int b = bi2 / 96, rem = bi2 - b * 96;
    int c0 = (rem >> 2) * 64, t0 = (rem & 3) * 64;
    const float* xb = x + ((size_t)b * CL + c0) * T + t0;
#pragma unroll
    for (int i = 0; i < 16; i++) {
      int idx = tid + i * 256, c = idx >> 6, t = idx & 63;
      xs[c][t] = xb[(size_t)c * T + t];
    }
    __syncthreads();
    unsigned short* ob = xT + ((size_t)b * T + t0) * CL + c0;
#pragma unroll
    for (int half = 0; half < 2; half++) {
      int s = tid + half * 256;
      int t = s >> 3, kg = s & 7;
      unsigned short v[8];
#pragma unroll
      for (int j = 0; j < 8; j++) v[j] = f2bf(xs[kg * 8 + j][t]);
      uint4 o = {(unsigned)v[0] | ((unsigned)v[1] << 16),
                 (unsigned)v[2] | ((unsigned)v[3] << 16),
                 (unsigned)v[4] | ((unsigned)v[5] << 16),
                 (unsigned)v[6] | ((unsigned)v[7] << 16)};
      *(uint4*)&ob[(size_t)t * CL + kg * 8] = o;
    }
  } else if (bi < 4928) {
    int idx = (bi - 4864) * 256 + tid;
    int b = idx & 31, o = idx >> 5;
    float s = 0.f;
    for (int c = 0; c < CG; c++) s = fmaf(gx[b * CG + c], gW1[o * CG + c], s);
    y1g[o * 32 + b] = s;
  } else {
    float4 z = {0.f, 0.f, 0.f, 0.f};
    ((float4*)bsum)[tid] = z;  // zeroes bsum[512] + bsq[512] (adjacent)
  }
}

// ============ 2: gemm1 dual MFMA (256thr, 128x128, BK=64, XOR-8 swizzle) ====
// grid: 512 GEMM blocks + 64 gnet2 blocks. 24 barrier iterations.
__global__ __launch_bounds__(256, 2) void k_gemm1(
    const unsigned short* __restrict__ xT, const unsigned short* __restrict__ Wc,
    unsigned short* __restrict__ y1u, unsigned short* __restrict__ ysb,
    float* __restrict__ bsum, float* __restrict__ bsq,
    const float* __restrict__ y1g, const float* __restrict__ gg1,
    const float* __restrict__ gb1, const float* __restrict__ gW2,
    const float* __restrict__ gb2, const float* __restrict__ gx,
    const float* __restrict__ gWsc, float* __restrict__ hg) {
  const int tid = threadIdx.x, bi = blockIdx.x;
  if (bi >= 512) {  // gnet2 with redundant per-block gbn (tiny)
    __shared__ float gsc[512], gsh[512];
#pragma unroll
    for (int jj = 0; jj < 2; jj++) {
      int o = tid + jj * 256;
      float s = 0.f, s2 = 0.f;
      for (int b = 0; b < 32; b++) {
        float v = y1g[o * 32 + b];
        s += v; s2 = fmaf(v, v, s2);
      }
      float mu = s * (1.f / 32.f);
      float var = s2 * (1.f / 32.f) - mu * mu;
      float sc = gg1[o] * rsqrtf(var + EPS);
      gsc[o] = sc;
      gsh[o] = gb1[o] - mu * sc;
    }
    __syncthreads();
    int idx = (bi - 512) * 256 + tid;
    int b = idx & 31, p = idx >> 5;
    float s = gb2[p];
    for (int o = 0; o < MI; o++) {
      float v = fmaxf(fmaf(y1g[o * 32 + b], gsc[o], gsh[o]), 0.f);
      s = fmaf(v, gW2[(size_t)p * MI + o], s);
    }
    for (int c = 0; c < CG; c++) s = fmaf(gx[b * CG + c], gWsc[p * CG + c], s);
    hg[p * 32 + b] = s;
    return;
  }
  __shared__ __align__(16) unsigned short As[128 * 64];  // 16 KB, 128B rows
  __shared__ __align__(16) unsigned short Bs[128 * 64];  // 16 KB
  const int w = tid >> 6, lane = tid & 63;
  const int m0 = (bi & 63) * 128, o0 = (bi >> 6) * 128;
  const int wm = w & 1, wn = w >> 1;
  const int lm = lane & 15, q = lane >> 4;
  // DMA: each inst covers 8 rows x 64 elems; lane l -> row l>>3, src chunk
  // (l&7)^(l>>3) so LDS slot s of row r holds global chunk s^(r&7).
  const int drow = lane >> 3;
  const int dchunk = (lane & 7) ^ drow;
  const int swz = lm & 7;  // fragment-read row XOR (row&7 == lm&7)
  f32x4 acc[4][4];
#pragma unroll
  for (int i = 0; i < 4; i++)
#pragma unroll
    for (int j = 0; j < 4; j++) acc[i][j] = f32x4{0.f, 0.f, 0.f, 0.f};

  const unsigned short* pa = xT + (size_t)(m0 + w * 32 + drow) * CL + dchunk * 8;
  const unsigned short* pb = Wc + (size_t)(o0 + w * 32 + drow) * CL + dchunk * 8;
  for (int k0 = 0; k0 < CL; k0 += 64) {
#pragma unroll
    for (int i = 0; i < 4; i++) {
      __builtin_amdgcn_global_load_lds(
          (const __attribute__((address_space(1))) void*)(pa + (size_t)i * 8 * CL + k0),
          (__attribute__((address_space(3))) void*)&As[(w * 32 + i * 8) * 64], 16, 0, 0);
      __builtin_amdgcn_global_load_lds(
          (const __attribute__((address_space(1))) void*)(pb + (size_t)i * 8 * CL + k0),
          (__attribute__((address_space(3))) void*)&Bs[(w * 32 + i * 8) * 64], 16, 0, 0);
    }
    __syncthreads();
#pragma unroll
    for (int kc = 0; kc < 2; kc++) {
      const int col = (((kc * 4 + q) ^ swz)) * 8;
      bf16x8 af[4], bfr[4];
#pragma unroll
      for (int mi = 0; mi < 4; mi++)
        af[mi] = *(const bf16x8*)&As[(wm * 64 + mi * 16 + lm) * 64 + col];
#pragma unroll
      for (int ni = 0; ni < 4; ni++)
        bfr[ni] = *(const bf16x8*)&Bs[(wn * 64 + ni * 16 + lm) * 64 + col];
#pragma unroll
      for (int mi = 0; mi < 4; mi++)
#pragma unroll
        for (int ni = 0; ni < 4; ni++)
          acc[mi][ni] = __builtin_amdgcn_mfma_f32_16x16x32_bf16(
              af[mi], bfr[ni], acc[mi][ni], 0, 0, 0);
    }
    __syncthreads();
  }
  const int row0 = m0 + wm * 64 + q * 4;
  const bool isY1 = (o0 < 512);
  unsigned short* dst = isY1 ? y1u : ysb;
  const int ob = isY1 ? o0 : o0 - 512;
#pragma unroll
  for (int mi = 0; mi < 4; mi++)
#pragma unroll
    for (int ni = 0; ni < 4; ni++) {
      int oc = ob + wn * 64 + ni * 16 + lm;
#pragma unroll
      for (int r = 0; r < 4; r++)
        dst[(size_t)(row0 + mi * 16 + r) * 512 + oc] = f2bf(acc[mi][ni][r]);
    }
  if (isY1) {  // BN stats: in-register col sums + q-shuffle + 1 atomic per col
#pragma unroll
    for (int ni = 0; ni < 4; ni++) {
      float s = 0.f, s2 = 0.f;
#pragma unroll
      for (int mi = 0; mi < 4; mi++)
#pragma unroll
        for (int r = 0; r < 4; r++) {
          float v = acc[mi][ni][r];
          s += v; s2 = fmaf(v, v, s2);
        }
      s += __shfl_xor(s, 16, 64);  s2 += __shfl_xor(s2, 16, 64);
      s += __shfl_xor(s, 32, 64);  s2 += __shfl_xor(s2, 32, 64);
      if (q == 0) {
        int c = o0 + wn * 64 + ni * 16 + lm;
        atomicAdd(&bsum[c], s);
        atomicAdd(&bsq[c], s2);
      }
    }
  }
}

// ============ 3: bnapply (v = bf16(relu(bn(y1)))) + gln piggyback ===========
__global__ __launch_bounds__(256) void k_bnapp(
    const unsigned short* __restrict__ y1u, const float* __restrict__ bsum,
    const float* __restrict__ bsq, const float* __restrict__ lg1,
    const float* __restrict__ lb1, unsigned short* __restrict__ vv,
    const float* __restrict__ hg, const float* __restrict__ glng,
    const float* __restrict__ glnb, unsigned short* __restrict__ gnormb) {
  __shared__ float rb[4];
  const int bi = blockIdx.x, tid = threadIdx.x;
  if (bi >= 4096) {  // gln
    int b = bi - 4096;
    float v0 = hg[tid * 32 + b];
    float v1 = hg[(tid + 256) * 32 + b];
    float s = block_sum(v0 + v1, rb);
    float s2 = block_sum(fmaf(v0, v0, v1 * v1), rb);
    float mu = s * (1.f / MI);
    float var = s2 * (1.f / MI) - mu * mu;
    float rstd = rsqrtf(var + EPS);
    float L0 = fmaf((v0 - mu) * rstd, glng[tid], glnb[tid]);
    float L1 = fmaf((v1 - mu) * rstd, glng[tid + 256], glnb[tid + 256]);
    float n2 = block_sum(fmaf(L0, L0, L1 * L1), rb);
    float inv = rsqrtf(n2);
    gnormb[b * MI + tid] = f2bf(L0 * inv);
    gnormb[b * MI + tid + 256] = f2bf(L1 * inv);
    return;
  }
  int idx = (bi * 256 + tid) * 4;
  int o = idx & 511;
  ushort4 in = *(const ushort4*)&y1u[idx];
  float iv[4] = {bf2f(in.x), bf2f(in.y), bf2f(in.z), bf2f(in.w)};
  unsigned short ov[4];
#pragma unroll
  for (int j = 0; j < 4; j++) {
    float mu = bsum[o + j] * (1.f / NPOS);
    float var = bsq[o + j] * (1.f / NPOS) - mu * mu;
    float sc = lg1[o + j] * rsqrtf(var + EPS);
    float sh = lb1[o + j] - mu * sc;
    ov[j] = f2bf(fmaxf(fmaf(iv[j], sc, sh), 0.f));
  }
  ushort4 out = {ov[0], ov[1], ov[2], ov[3]};
  *(ushort4*)&vv[idx] = out;
}

// ============ 4: gemm2 (256thr, 128x128, BK=64, XOR-8 swizzle) ==============
__global__ __launch_bounds__(256, 2) void k_gemm2(
    const unsigned short* __restrict__ vv, const unsigned short* __restrict__ W2b,
    const float* __restrict__ b2, unsigned short* __restrict__ hb16) {
  __shared__ __align__(16) unsigned short As[128 * 64];
  __shared__ __align__(16) unsigned short Bs[128 * 64];
  const int tid = threadIdx.x, bi = blockIdx.x;
  const int w = tid >> 6, lane = tid & 63;
  const int m0 = (bi & 63) * 128, p0 = (bi >> 6) * 128;
  const int wm = w & 1, wn = w >> 1;
  const int lm = lane & 15, q = lane >> 4;
  const int drow = lane >> 3;
  const int dchunk = (lane & 7) ^ drow;
  const int swz = lm & 7;
  f32x4 acc[4][4];
#pragma unroll
  for (int i = 0; i < 4; i++)
#pragma unroll
    for (int j = 0; j < 4; j++) acc[i][j] = f32x4{0.f, 0.f, 0.f, 0.f};

  const unsigned short* pa = vv + (size_t)(m0 + w * 32 + drow) * 512 + dchunk * 8;
  const unsigned short* pb = W2b + (size_t)(p0 + w * 32 + drow) * 512 + dchunk * 8;
  for (int k0 = 0; k0 < 512; k0 += 64) {
#pragma unroll
    for (int i = 0; i < 4; i++) {
      __builtin_amdgcn_global_load_lds(
          (const __attribute__((address_space(1))) void*)(pa + (size_t)i * 8 * 512 + k0),
          (__attribute__((address_space(3))) void*)&As[(w * 32 + i * 8) * 64], 16, 0, 0);
      __builtin_amdgcn_global_load_lds(
          (const __attribute__((address_space(1))) void*)(pb + (size_t)i * 8 * 512 + k0),
          (__attribute__((address_space(3))) void*)&Bs[(w * 32 + i * 8) * 64], 16, 0, 0);
    }
    __syncthreads();
#pragma unroll
    for (int kc = 0; kc < 2; kc++) {
      const int col = (((kc * 4 + q) ^ swz)) * 8;
      bf16x8 af[4], bfr[4];
#pragma unroll
      for (int mi = 0; mi < 4; mi++)
        af[mi] = *(const bf16x8*)&As[(wm * 64 + mi * 16 + lm) * 64 + col];
#pragma unroll
      for (int ni = 0; ni < 4; ni++)
        bfr[ni] = *(const bf16x8*)&Bs[(wn * 64 + ni * 16 + lm) * 64 + col];
#pragma unroll
      for (int mi = 0; mi < 4; mi++)
#pragma unroll
        for (int ni = 0; ni < 4; ni++)
          acc[mi][ni] = __builtin_amdgcn_mfma_f32_16x16x32_bf16(
              af[mi], bfr[ni], acc[mi][ni], 0, 0, 0);
    }
    __syncthreads();
  }
  const int row0 = m0 + wm * 64 + q * 4;
#pragma unroll
  for (int ni = 0; ni < 4; ni++) {
    int p = p0 + wn * 64 + ni * 16 + lm;
    float bias = b2[p];
#pragma unroll
    for (int mi = 0; mi < 4; mi++)
#pragma unroll
      for (int r = 0; r < 4; r++) {
        size_t off = (size_t)(row0 + mi * 16 + r) * 512 + p;
        hb16[off] = f2bf(acc[mi][ni][r] + bias);  // +ys added in tail
      }
  }
}

// ============ 5: tail = (+ys) LN + U-tile MFMA + positives + partials =======
__global__ __launch_bounds__(256) void k_tail(
    const unsigned short* __restrict__ hb16, const unsigned short* __restrict__ ysb,
    const float* __restrict__ lng, const float* __restrict__ lnb,
    const unsigned short* __restrict__ gnormb,
    float* __restrict__ up, float* __restrict__ pmax, float* __restrict__ psum) {
  __shared__ __align__(16) unsigned short gs[32 * 512];
  __shared__ __align__(16) unsigned short Ls[32 * 512];
  __shared__ float Ured[4 * 1024];
  const int tid = threadIdx.x;
  const int w = tid >> 6, lane = tid & 63;
  const int r0 = blockIdx.x * 32;
  const int smp = r0 >> 8;
#pragma unroll
  for (int i = 0; i < 8; i++) {
    int e = (tid + i * 256) * 8;
    *(uint4*)&gs[e] = *(const uint4*)&gnormb[e];
  }
  float4 g0 = *(const float4*)&lng[lane * 8];
  float4 g1 = *(const float4*)&lng[lane * 8 + 4];
  float4 bb0 = *(const float4*)&lnb[lane * 8];
  float4 bb1 = *(const float4*)&lnb[lane * 8 + 4];
  float gg[8] = {g0.x, g0.y, g0.z, g0.w, g1.x, g1.y, g1.z, g1.w};
  float bz[8] = {bb0.x, bb0.y, bb0.z, bb0.w, bb1.x, bb1.y, bb1.z, bb1.w};
#pragma unroll
  for (int j = 0; j < 8; j++) {
    int rr = w * 8 + j;
    size_t off = (size_t)(r0 + rr) * 512 + lane * 8;
    uint4 hu = *(const uint4*)&hb16[off];
    uint4 yu = *(const uint4*)&ysb[off];
    unsigned short hv[8] = {
        (unsigned short)(hu.x & 0xffff), (unsigned short)(hu.x >> 16),
        (unsigned short)(hu.y & 0xffff), (unsigned short)(hu.y >> 16),
        (unsigned short)(hu.z & 0xffff), (unsigned short)(hu.z >> 16),
        (unsigned short)(hu.w & 0xffff), (unsigned short)(hu.w >> 16)};
    unsigned short yv[8] = {
        (unsigned short)(yu.x & 0xffff), (unsigned short)(yu.x >> 16),
        (unsigned short)(yu.y & 0xffff), (unsigned short)(yu.y >> 16),
        (unsigned short)(yu.z & 0xffff), (unsigned short)(yu.z >> 16),
        (unsigned short)(yu.w & 0xffff), (unsigned short)(yu.w >> 16)};
    float v[8];
    float s = 0.f, s2 = 0.f;
#pragma unroll
    for (int k = 0; k < 8; k++) {
      v[k] = bf2f(hv[k]) + bf2f(yv[k]);
      s += v[k]; s2 = fmaf(v[k], v[k], s2);
    }
    s = wave_sum(s);
    s2 = wave_sum(s2);
    float mu = s * (1.f / MI);
    float var = s2 * (1.f / MI) - mu * mu;
    float rstd = rsqrtf(var + EPS);
    float L[8], n2 = 0.f;
#pragma unroll
    for (int k = 0; k < 8; k++) {
      L[k] = fmaf((v[k] - mu) * rstd, gg[k], bz[k]);
      n2 = fmaf(L[k], L[k], n2);
    }
    n2 = wave_sum(n2);
    float inv = rsqrtf(n2);
    unsigned short* orow = &Ls[rr * 512 + lane * 8];
    ushort4 o0 = {f2bf(L[0] * inv), f2bf(L[1] * inv), f2bf(L[2] * inv), f2bf(L[3] * inv)};
    ushort4 o1 = {f2bf(L[4] * inv), f2bf(L[5] * inv), f2bf(L[6] * inv), f2bf(L[7] * inv)};
    *(ushort4*)orow = o0;
    *(ushort4*)(orow + 4) = o1;
  }
  __syncthreads();
  const int lm = lane & 15, q = lane >> 4;
  f32x4 acc[2][2];
#pragma unroll
  for (int i = 0; i < 2; i++)
#pragma unroll
    for (int j = 0; j < 2; j++) acc[i][j] = f32x4{0.f, 0.f, 0.f, 0.f};
#pragma unroll
  for (int kk = 0; kk < 4; kk++) {
    int k0 = w * 128 + kk * 32 + q * 8;
    bf16x8 af[2], bfr[2];
#pragma unroll
    for (int mi = 0; mi < 2; mi++)
      af[mi] = *(const bf16x8*)&gs[(mi * 16 + lm) * 512 + k0];
#pragma unroll
    for (int ni = 0; ni < 2; ni++)
      bfr[ni] = *(const bf16x8*)&Ls[(ni * 16 + lm) * 512 + k0];
#pragma unroll
    for (int mi = 0; mi < 2; mi++)
#pragma unroll
      for (int ni = 0; ni < 2; ni++)
        acc[mi][ni] = __builtin_amdgcn_mfma_f32_16x16x32_bf16(
            af[mi], bfr[ni], acc[mi][ni], 0, 0, 0);
  }
#pragma unroll
  for (int mi = 0; mi < 2; mi++)
#pragma unroll
    for (int ni = 0; ni < 2; ni++)
#pragma unroll
      for (int r = 0; r < 4; r++) {
        int m = mi * 16 + q * 4 + r, n = ni * 16 + lm;
        Ured[w * 1024 + m * 32 + n] = acc[mi][ni][r];
      }
  __syncthreads();
  float u[4];
#pragma unroll
  for (int j = 0; j < 4; j++) {
    int idx = tid * 4 + j;
    u[j] = Ured[idx] + Ured[1024 + idx] + Ured[2048 + idx] + Ured[3072 + idx];
  }
  __syncthreads();
#pragma unroll
  for (int j = 0; j < 4; j++) Ured[tid * 4 + j] = u[j];
  int m = (tid * 4) >> 5;
  if (m == smp) {
#pragma unroll
    for (int j = 0; j < 4; j++)
      up[r0 + ((tid * 4 + j) & 31)] = u[j] * (1.f / TEMP);
  }
  __syncthreads();
  if (tid < 32) {
    float mx = -1e30f, s = 0.f;
    if (tid != smp) {
      for (int n = 0; n < 32; n++) mx = fmaxf(mx, Ured[tid * 32 + n]);
      for (int n = 0; n < 32; n++) s += expf(Ured[tid * 32 + n] - mx);
    }
    pmax[tid * 256 + blockIdx.x] = mx;
    psum[tid * 256 + blockIdx.x] = s;
  }
}

// ============ 6: loss = mean(lse - u_p), combining 256 partials/row =========
__global__ __launch_bounds__(256) void k_loss(
    const float* __restrict__ up, const float* __restrict__ pmax,
    const float* __restrict__ psum, float* __restrict__ out) {
  __shared__ float rb[4];
  __shared__ float red[32][8];
  __shared__ float Ms[32], Ss[32];
  const int tid = threadIdx.x;
  const int n = tid >> 3, j = tid & 7;
  float mx = -1e30f;
  for (int c = j * 32; c < j * 32 + 32; c++) mx = fmaxf(mx, pmax[n * 256 + c]);
  red[n][j] = mx;
  __syncthreads();
  if (j == 0) {
    float M = -1e30f;
#pragma unroll
    for (int k = 0; k < 8; k++) M = fmaxf(M, red[n][k]);
    Ms[n] = M;
  }
  __syncthreads();
  float M = Ms[n];
  float s = 0.f;
  for (int c = j * 32; c < j * 32 + 32; c++)
    s += psum[n * 256 + c] * expf(pmax[n * 256 + c] - M);
  __syncthreads();
  red[n][j] = s;
  __syncthreads();
  if (j == 0) {
    float S = 0.f;
#pragma unroll
    for (int k = 0; k < 8; k++) S += red[n][k];
    Ss[n] = S;
  }
  __syncthreads();
  float acc = 0.f;
  for (int i = tid; i < NPOS; i += 256) {
    int nn = i >> 8;
    float upv = up[i];
    float Mn = Ms[nn], Sn = Ss[nn];
    float mx2 = fmaxf(upv, Mn);
    float lse = mx2 + logf(expf(upv - mx2) + Sn * expf(Mn - mx2));
    acc += lse - upv;
  }
  acc = block_sum(acc, rb);
  if (tid == 0) out[0] = acc * (1.f / NPOS);
}

extern "C" void kernel_launch(void* const* d_in, const int* in_sizes, int n_in,
                              void* d_out, int out_size, void* d_ws, size_t ws_size,
                              hipStream_t stream) {
  (void)in_sizes; (void)n_in; (void)out_size; (void)ws_size;
  const float* x    = (const float*)d_in[0];
  const float* gx   = (const float*)d_in[1];
  const float* lW1  = (const float*)d_in[2];
  const float* lg1  = (const float*)d_in[3];
  const float* lb1  = (const float*)d_in[4];
  const float* lW2  = (const float*)d_in[5];
  const float* lb2  = (const float*)d_in[6];
  const float* lWs  = (const float*)d_in[7];
  const float* llng = (const float*)d_in[8];
  const float* llnb = (const float*)d_in[9];
  const float* gW1  = (const float*)d_in[10];
  const float* gg1  = (const float*)d_in[11];
  const float* gb1  = (const float*)d_in[12];
  const float* gW2  = (const float*)d_in[13];
  const float* gb2  = (const float*)d_in[14];
  const float* gWs  = (const float*)d_in[15];
  const float* glng = (const float*)d_in[16];
  const float* glnb = (const float*)d_in[17];

  char* wsb = (char*)d_ws;
  unsigned short* xT     = (unsigned short*)(wsb);             // [8192][1536] bf16
  unsigned short* Wc     = (unsigned short*)(wsb + 25165824);  // [1024][1536] bf16
  unsigned short* W2b    = (unsigned short*)(wsb + 28311552);  // [512][512] bf16
  unsigned short* y1u    = (unsigned short*)(wsb + 28835840);  // [8192][512] bf16
  unsigned short* ysb    = (unsigned short*)(wsb + 37224448);  // [8192][512] bf16
  unsigned short* vv     = (unsigned short*)(wsb + 45613056);  // [8192][512] bf16
  unsigned short* hb16   = (unsigned short*)(wsb + 54001664);  // [8192][512] bf16
  float* bsum            = (float*)(wsb + 62390272);           // [512]
  float* bsq             = (float*)(wsb + 62392320);           // [512]
  float* y1g             = (float*)(wsb + 62394368);           // [512][32]
  float* hg              = (float*)(wsb + 62459904);           // [512][32]
  unsigned short* gnormb = (unsigned short*)(wsb + 62525440);  // [32][512] bf16
  float* up              = (float*)(wsb + 62558208);           // [8192]
  float* pmax            = (float*)(wsb + 62590976);           // [32][256]
  float* psum            = (float*)(wsb + 62623744);           // [32][256]

  k_prep<<<dim3(4929), 256, 0, stream>>>(x, lW1, lWs, lW2, gx, gW1, xT, Wc, W2b,
                                         y1g, bsum);
  k_gemm1<<<dim3(576), 256, 0, stream>>>(xT, Wc, y1u, ysb, bsum, bsq,
                                         y1g, gg1, gb1, gW2, gb2, gx, gWs, hg);
  k_bnapp<<<dim3(4128), 256, 0, stream>>>(y1u, bsum, bsq, lg1, lb1, vv,
                                          hg, glng, glnb, gnormb);
  k_gemm2<<<dim3(256), 256, 0, stream>>>(vv, W2b, lb2, hb16);
  k_tail<<<dim3(256), 256, 0, stream>>>(hb16, ysb, llng, llnb, gnormb,
                                        up, pmax, psum);
  k_loss<<<dim3(1), 256, 0, stream>>>(up, pmax, psum, (float*)d_out);
}